// Round 5
// baseline (341.808 us; speedup 1.0000x reference)
//
#include <hip/hip_runtime.h>
#include <climits>

typedef __attribute__((ext_vector_type(8))) short s8;      // 8 bf16 = 4 VGPRs
typedef __attribute__((ext_vector_type(4))) float f32x4;   // MFMA acc

#define BQ    256
#define DDIM  256
#define NBANK 100000
#define BN    64                          // bank cols per block (4 col-tiles of 16)
#define NJB   ((NBANK + BN - 1) / BN)     // 1563
#define SENT  1e30f
#define INIT64 0xFFFFFFFFFFFFFFFFULL

// Split fp32 x into bf16 hi (round-half-up) + bf16 lo: x ~= hi + lo, |err| <~ 2^-18|x|
__device__ inline void splitElem(float x, s8& h, s8& l, int i) {
    unsigned u  = __float_as_uint(x);
    unsigned uh = (u + 0x8000u) & 0xFFFF0000u;
    h[i] = (short)(uh >> 16);
    float lf = x - __uint_as_float(uh);            // exact
    l[i] = (short)((__float_as_uint(lf) + 0x8000u) >> 16);
}

__device__ inline void split8(const float4 v0, const float4 v1, s8& h, s8& l) {
    splitElem(v0.x, h, l, 0); splitElem(v0.y, h, l, 1);
    splitElem(v0.z, h, l, 2); splitElem(v0.w, h, l, 3);
    splitElem(v1.x, h, l, 4); splitElem(v1.y, h, l, 5);
    splitElem(v1.z, h, l, 6); splitElem(v1.w, h, l, 7);
}

__device__ inline float sq8(const float4 v0, const float4 v1, float s) {
    s = fmaf(v0.x, v0.x, s); s = fmaf(v0.y, v0.y, s);
    s = fmaf(v0.z, v0.z, s); s = fmaf(v0.w, v0.w, s);
    s = fmaf(v1.x, v1.x, s); s = fmaf(v1.y, v1.y, s);
    s = fmaf(v1.z, v1.z, s); s = fmaf(v1.w, v1.w, s);
    return s;
}

// Monotone fp32->u32 (smaller float => smaller uint), pack with index:
// min over packed u64 == (min value, then min index). Exact argmin semantics.
__device__ inline unsigned long long packMin(float v, int idx) {
    unsigned b = __float_as_uint(v);
    unsigned u = (b & 0x80000000u) ? ~b : (b | 0x80000000u);
    return ((unsigned long long)u << 32) | (unsigned)idx;
}

// Kernel 0: blocks 0-15 pre-split A into MFMA-A-fragment-ordered bf16 hi/lo;
// block 16 initializes the 512 atomic argmin slots.
__global__ __launch_bounds__(512) void prep(
    const float* __restrict__ feature, s8* __restrict__ fH, s8* __restrict__ fL,
    unsigned long long* __restrict__ slots)
{
    if (blockIdx.x == 16) {
        slots[threadIdx.x] = INIT64;     // 512 slots: [0..255]=primary, [256..511]=diff
        return;
    }
    const int t    = blockIdx.x * 512 + threadIdx.x;   // 0..8191
    const int lane = t & 63, ks = (t >> 6) & 7, rt = t >> 9;
    const int row  = rt * 16 + (lane & 15);
    const int k0   = ks * 32 + (lane >> 4) * 8;
    const float* p = feature + (size_t)row * DDIM + k0;
    const float4 v0 = *(const float4*)p;
    const float4 v1 = *(const float4*)(p + 4);
    s8 h, l;
    split8(v0, v1, h, l);
    fH[t] = h; fL[t] = l;
}

// Kernel 1: split-bf16 MFMA GEMM + fused masked argmin via packed atomicMin.
// 256 threads = 4 waves; wave w owns rows w*64..+63. Full-K B tile staged in
// LDS once (64 KB, hi+lo, fragment layout) -> ONE barrier, then pure
// ds_read/MFMA stream with 1-slice-ahead A prefetch (L2-resident fH/fL).
__global__ __launch_bounds__(256, 2) void gemm_argmin(
    const s8* __restrict__ fH, const s8* __restrict__ fL,
    const float* __restrict__ bank,
    const int* __restrict__ cluster_label, const int* __restrict__ class_label,
    const int* __restrict__ cluster_idx,  const int* __restrict__ gt_label,
    unsigned long long* __restrict__ slots)
{
    __shared__ __align__(16) s8 bHs[8 * 4 * 64];   // [slice][ct][fraglane] 32 KB
    __shared__ __align__(16) s8 bLs[8 * 4 * 64];   // 32 KB
    __shared__ float b2s[BN];
    __shared__ int clsS[BN], cluS[BN], rowGt[BQ], rowClu[BQ];

    const int tid = threadIdx.x;
    const int jb  = blockIdx.x;
    const int j0  = jb * BN;

    if (tid < BN) {
        int jg = j0 + tid;
        int jc = jg < NBANK ? jg : NBANK - 1;
        clsS[tid] = class_label[jc];
        cluS[tid] = cluster_label[jc];
    }
    rowGt[tid]  = gt_label[tid];
    rowClu[tid] = cluster_idx[tid];

    // ---- Stage B (full K): thread covers col=tid>>2, k-octet q of every slice
    const int col = tid >> 2, q = tid & 3;
    {
        int jcol = j0 + col;
        jcol = jcol < NBANK ? jcol : NBANK - 1;
        const float* gb = bank + (size_t)jcol * DDIM + q * 8;
        float4 v[8][2];
        #pragma unroll
        for (int s = 0; s < 8; ++s) {          // 16 loads, all in flight
            v[s][0] = *(const float4*)(gb + s * 32);
            v[s][1] = *(const float4*)(gb + s * 32 + 4);
        }
        const int ct_s = col >> 4, cl_s = col & 15;
        const int wi   = ct_s * 64 + q * 16 + cl_s;
        float sqa = 0.f;
        #pragma unroll
        for (int s = 0; s < 8; ++s) {
            s8 h, l;
            split8(v[s][0], v[s][1], h, l);
            sqa = sq8(v[s][0], v[s][1], sqa);
            bHs[s * 256 + wi] = h;
            bLs[s * 256 + wi] = l;
        }
        sqa += __shfl_xor(sqa, 1);             // q-threads are adjacent lanes
        sqa += __shfl_xor(sqa, 2);
        if (q == 0) b2s[col] = sqa;
    }
    __syncthreads();                           // the only barrier

    // ---- Compute: wave w, lane; g = k-octet/row-quad, c = col-in-tile
    const int w = tid >> 6, lane = tid & 63;
    const int g = lane >> 4, c = lane & 15;

    f32x4 acc[4][4];
    #pragma unroll
    for (int ct = 0; ct < 4; ++ct)
        #pragma unroll
        for (int rt = 0; rt < 4; ++rt)
            acc[ct][rt] = (f32x4){0.f, 0.f, 0.f, 0.f};

    s8 aH[4], aL[4], nH[4], nL[4];
    #pragma unroll
    for (int rt = 0; rt < 4; ++rt) {
        aH[rt] = fH[((w * 4 + rt) * 8 + 0) * 64 + lane];
        aL[rt] = fL[((w * 4 + rt) * 8 + 0) * 64 + lane];
    }
    #pragma unroll
    for (int s = 0; s < 8; ++s) {
        if (s < 7) {
            #pragma unroll
            for (int rt = 0; rt < 4; ++rt) {   // prefetch next slice's A frags (L2)
                nH[rt] = fH[((w * 4 + rt) * 8 + s + 1) * 64 + lane];
                nL[rt] = fL[((w * 4 + rt) * 8 + s + 1) * 64 + lane];
            }
        }
        #pragma unroll
        for (int ct = 0; ct < 4; ++ct) {
            const s8 bh = bHs[s * 256 + ct * 64 + lane];
            const s8 bl = bLs[s * 256 + ct * 64 + lane];
            #pragma unroll
            for (int rt = 0; rt < 4; ++rt) {
                acc[ct][rt] = __builtin_amdgcn_mfma_f32_16x16x32_bf16(aH[rt], bh, acc[ct][rt], 0, 0, 0);
                acc[ct][rt] = __builtin_amdgcn_mfma_f32_16x16x32_bf16(aH[rt], bl, acc[ct][rt], 0, 0, 0);
                acc[ct][rt] = __builtin_amdgcn_mfma_f32_16x16x32_bf16(aL[rt], bh, acc[ct][rt], 0, 0, 0);
                acc[ct][rt] = __builtin_amdgcn_mfma_f32_16x16x32_bf16(aL[rt], bl, acc[ct][rt], 0, 0, 0);
            }
        }
        #pragma unroll
        for (int rt = 0; rt < 4; ++rt) { aH[rt] = nH[rt]; aL[rt] = nL[rt]; }
    }

    // ---- Epilogue: C/D layout col=lane&15, row=g*4+reg (HW-verified, absmax 0 R3/R4)
    #pragma unroll
    for (int rt = 0; rt < 4; ++rt) {
        #pragma unroll
        for (int r = 0; r < 4; ++r) {
            const int row  = w * 64 + rt * 16 + g * 4 + r;
            const int myGt = rowGt[row], myClu = rowClu[row];
            float bpv = SENT, bdv = SENT;
            int   bpi = INT_MAX, bdi = INT_MAX;
            #pragma unroll
            for (int ct = 0; ct < 4; ++ct) {   // ascending ct = ascending col per lane
                const int jg = j0 + ct * 16 + c;
                const float sc = b2s[ct * 16 + c] - 2.f * acc[ct][rt][r];
                if (jg < NBANK && clsS[ct * 16 + c] != myGt) {
                    if (sc < bdv) { bdv = sc; bdi = jg; }
                    if (cluS[ct * 16 + c] == myClu && sc < bpv) { bpv = sc; bpi = jg; }
                }
            }
            #pragma unroll
            for (int off = 1; off < 16; off <<= 1) {   // tie-aware 16-lane reduce
                float vv = __shfl_xor(bpv, off); int ii = __shfl_xor(bpi, off);
                if (vv < bpv || (vv == bpv && ii < bpi)) { bpv = vv; bpi = ii; }
                vv = __shfl_xor(bdv, off); ii = __shfl_xor(bdi, off);
                if (vv < bdv || (vv == bdv && ii < bdi)) { bdv = vv; bdi = ii; }
            }
            if (c == 0) {
                if (bpi != INT_MAX) {
                    const unsigned long long pk = packMin(bpv, bpi);
                    const unsigned long long cur =
                        *(const volatile unsigned long long*)(slots + row);
                    if (pk < cur) atomicMin(slots + row, pk);   // guarded: ~lnN updates/row
                }
                if (bdi != INT_MAX) {
                    const unsigned long long pk = packMin(bdv, bdi);
                    const unsigned long long cur =
                        *(const volatile unsigned long long*)(slots + 256 + row);
                    if (pk < cur) atomicMin(slots + 256 + row, pk);
                }
            }
        }
    }
}

// Kernel 2: decode slots (primary else fallback), gather bank row.
__global__ __launch_bounds__(256) void gather(
    const unsigned long long* __restrict__ slots,
    const float* __restrict__ bank, float* __restrict__ out)
{
    const int row = blockIdx.x, t = threadIdx.x;
    __shared__ int sIdx;
    if (t == 0) {
        unsigned long long p = slots[row];
        unsigned long long d = slots[256 + row];
        unsigned long long chosen = (p != INIT64) ? p : d;
        sIdx = (chosen != INIT64) ? (int)(unsigned)(chosen & 0xFFFFFFFFu) : 0;
    }
    __syncthreads();
    out[row * DDIM + t] = bank[(size_t)sIdx * DDIM + t];
}

extern "C" void kernel_launch(void* const* d_in, const int* in_sizes, int n_in,
                              void* d_out, int out_size, void* d_ws, size_t ws_size,
                              hipStream_t stream) {
    const float* feature       = (const float*)d_in[0];
    const float* bank          = (const float*)d_in[1];
    const int*   cluster_label = (const int*)d_in[2];
    const int*   class_label   = (const int*)d_in[3];
    const int*   cluster_idx   = (const int*)d_in[4];
    const int*   gt_label      = (const int*)d_in[5];
    float* out = (float*)d_out;

    // Workspace: fH/fL (128 KB each) + 512 u64 slots (4 KB)
    s8* fH = (s8*)d_ws;                 // 8192 frags
    s8* fL = fH + 8192;
    unsigned long long* slots = (unsigned long long*)(fL + 8192);

    hipLaunchKernelGGL(prep, dim3(17), dim3(512), 0, stream, feature, fH, fL, slots);
    hipLaunchKernelGGL(gemm_argmin, dim3(NJB), dim3(256), 0, stream,
                       fH, fL, bank, cluster_label, class_label, cluster_idx, gt_label,
                       slots);
    hipLaunchKernelGGL(gather, dim3(BQ), dim3(256), 0, stream, slots, bank, out);
}